// Round 7
// baseline (407.712 us; speedup 1.0000x reference)
//
#include <hip/hip_runtime.h>
#include <stdint.h>

// ---------------------------------------------------------------------------
// ShiftedWindowAttention: B=32, H=W=64, C=256, heads=8, hd=32, ws=8, shift=4.
// Pipeline (v6): SINGLE fused kernel per window + tiny prep kernels.
//   cvtw   (weights f32->bf16, merged wqkv+wout)
//   bias   (pos_enc -> transposed/interleaved bias+mask table, f32)
//   swattn (block = window, 512 thr, 8 waves, wave = head, 128 KB LDS:
//           A 64x256 staged once (32KB swizzled, reused as P after QKV);
//           per-wave QKV GEMM N=96, B global->VGPR dbuf, no K-loop barriers;
//           q/k/v wave-private 12KB slices; attn (QK^T, bias, softmax,
//           2-pass P roundtrip in A region, PV); AO -> LDS q-slot;
//           oproj phase: out = AO @ wo^T + b with merge/inv-roll scatter.
//           3 barriers total; AO never touches HBM.)
// ---------------------------------------------------------------------------

typedef short short8 __attribute__((ext_vector_type(8)));
typedef short s16x4 __attribute__((ext_vector_type(4)));
typedef float f32x4 __attribute__((ext_vector_type(4)));

#define SCALE 0.17677669529663687f

__device__ __forceinline__ uint16_t f2bf(float f) {
  union { float f; uint32_t u; } c; c.f = f;
  uint32_t r = c.u + 0x7FFFu + ((c.u >> 16) & 1u);   // RNE
  return (uint16_t)(r >> 16);
}

// ---- weights f32 -> bf16 (wqkv and wout merged; outputs contiguous in ws)
__global__ __launch_bounds__(256) void cvtw_kernel(const float* __restrict__ wq,
                                                   const float* __restrict__ wo,
                                                   uint16_t* __restrict__ out) {
  int i = (blockIdx.x * 256 + threadIdx.x) * 8;       // grid 128 -> 262144 elems
  const float* src = (i < 196608) ? (wq + i) : (wo + (i - 196608));
  f32x4 a = *(const f32x4*)src;
  f32x4 b = *(const f32x4*)(src + 4);
  short8 v;
  v[0] = (short)f2bf(a[0]); v[1] = (short)f2bf(a[1]);
  v[2] = (short)f2bf(a[2]); v[3] = (short)f2bf(a[3]);
  v[4] = (short)f2bf(b[0]); v[5] = (short)f2bf(b[1]);
  v[6] = (short)f2bf(b[2]); v[7] = (short)f2bf(b[3]);
  *(short8*)(out + i) = v;
}

// ---- bias+mask table, transposed+interleaved: bm[wd][head][kk][a(16)][ni(4)]
__global__ __launch_bounds__(256) void bias_kernel(const float* __restrict__ pe,
                                                   float* __restrict__ bm) {
  int bx = blockIdx.x;              // wd*8 + head
  int wd = bx >> 3, head = bx & 7;
  int hw = wd >> 3, ww = wd & 7;
  int tid = threadIdx.x;
  int kk = tid >> 2, a0 = (tid & 3) * 4;
  int jy = kk >> 3, jx = kk & 7;
  int hj = hw * 8 + jy, xj = ww * 8 + jx;
  int rj = (hj >= 60 ? 2 : (hj >= 56 ? 1 : 0)) * 3 + (xj >= 60 ? 2 : (xj >= 56 ? 1 : 0));
  float* dst = bm + (size_t)bx * 4096 + kk * 64 + a0 * 4;
  for (int aa = 0; aa < 4; ++aa) {
    int a = a0 + aa;
    f32x4 v;
#pragma unroll
    for (int ni = 0; ni < 4; ++ni) {
      int i = ni * 16 + a;
      int iy = i >> 3, ix = i & 7;
      int hi = hw * 8 + iy, xi = ww * 8 + ix;
      int ri = (hi >= 60 ? 2 : (hi >= 56 ? 1 : 0)) * 3 + (xi >= 60 ? 2 : (xi >= 56 ? 1 : 0));
      v[ni] = (ri != rj) ? -1e30f : pe[head * 225 + (iy - jy + 7) * 15 + (ix - jx + 7)];
    }
    *(f32x4*)(dst + aa * 4) = v;
  }
}

// ---- FULLY FUSED per-window kernel: cvtx + qkv + attention + out-proj.
//      512 threads, 8 waves (wave = head). 128 KB LDS -> 1 block/CU.
__global__ __launch_bounds__(512, 2) void swattn_kernel(
    const float* __restrict__ x, const uint16_t* __restrict__ wq,
    const uint16_t* __restrict__ wo, const float* __restrict__ bqkv,
    const float* __restrict__ bout, const float* __restrict__ bm,
    float* __restrict__ out) {
  __shared__ uint16_t sm[65536];                 // 128 KB
  uint16_t* As = sm;                             // 32KB: A [8ks][64t][32k] swz; later P[8][2048]
  const int tid = threadIdx.x, lane = tid & 63, wv = tid >> 6;
  const int quad = lane >> 4, l15 = lane & 15;
  const int w = blockIdx.x;                      // window 0..2047
  const int h = wv;                              // this wave's head
  const int wd = w & 63, bb = w >> 6;
  f32x4 zero = {0.f, 0.f, 0.f, 0.f};

  // ---- stage A: roll(-4,-4)+window gather f32 -> bf16 -> swizzled LDS (once)
  {
    const int row = tid >> 3;                    // 64 rows, 8 threads each
    const int cg = tid & 7;
    int hy = (wd >> 3) * 8 + (row >> 3);
    int xx = (wd & 7) * 8 + (row & 7);
    const float* sp = x + (size_t)(bb * 4096 + (((hy + 4) & 63) << 6) + ((xx + 4) & 63)) * 256;
    int psw = (row >> 1) & 3;
#pragma unroll
    for (int j = 0; j < 4; ++j) {
      int c0 = cg * 8 + j * 64;
      f32x4 a = *(const f32x4*)(sp + c0);
      f32x4 d = *(const f32x4*)(sp + c0 + 4);
      short8 v;
      v[0] = (short)f2bf(a[0]); v[1] = (short)f2bf(a[1]);
      v[2] = (short)f2bf(a[2]); v[3] = (short)f2bf(a[3]);
      v[4] = (short)f2bf(d[0]); v[5] = (short)f2bf(d[1]);
      v[6] = (short)f2bf(d[2]); v[7] = (short)f2bf(d[3]);
      int ks = c0 >> 5, g = (c0 >> 3) & 3;
      *(short8*)&As[(ks * 64 + row) * 32 + ((g ^ psw) << 3)] = v;
    }
  }

  const int fsw = (quad ^ ((l15 >> 1) & 3)) << 3;  // conflict-free frag granule
  uint16_t* qk = sm + 16384 + wv * 6144;           // wave-private: q|k|v (12KB)

  // B rows for this wave: sec*256 + h*32 + (ni&1)*16 + l15  (sec = ni>>1)
  const uint16_t* bb0 = wq + (size_t)(h * 32 + l15) * 256 + quad * 8;

  short8 bfr[2][6];
#pragma unroll
  for (int ni = 0; ni < 6; ++ni)
    bfr[0][ni] = *(const short8*)(bb0 + (ni >> 1) * 65536 + (ni & 1) * 4096);

  f32x4 acc[4][6];
#pragma unroll
  for (int mi = 0; mi < 4; ++mi)
#pragma unroll
    for (int ni = 0; ni < 6; ++ni) acc[mi][ni] = zero;

  __syncthreads();                               // barrier 1: A resident

#pragma unroll
  for (int ks = 0; ks < 8; ++ks) {
    const int cur = ks & 1;
    if (ks < 7) {                                // register prefetch next k-step
#pragma unroll
      for (int ni = 0; ni < 6; ++ni)
        bfr[cur ^ 1][ni] = *(const short8*)(bb0 + (ni >> 1) * 65536 + (ni & 1) * 4096 + (ks + 1) * 32);
    }
    short8 af[4];
#pragma unroll
    for (int mi = 0; mi < 4; ++mi)
      af[mi] = *(const short8*)&As[(ks * 64 + mi * 16 + l15) * 32 + fsw];
#pragma unroll
    for (int mi = 0; mi < 4; ++mi)
#pragma unroll
      for (int ni = 0; ni < 6; ++ni)
        acc[mi][ni] = __builtin_amdgcn_mfma_f32_16x16x32_bf16(af[mi], bfr[cur][ni], acc[mi][ni], 0, 0, 0);
  }

  // ---- epilogue: bias add, q/k ([t][32] swz) + v ([d][t] swz) to private LDS
  float bqv[6];
#pragma unroll
  for (int ni = 0; ni < 6; ++ni)
    bqv[ni] = bqkv[(ni >> 1) * 256 + h * 32 + (ni & 1) * 16 + l15];

#pragma unroll
  for (int ni = 0; ni < 4; ++ni) {               // q (ni 0,1), k (ni 2,3)
    uint16_t* dst = qk + (ni >> 1) * 2048;
    int d = (ni & 1) * 16 + l15, dg = d >> 3;
#pragma unroll
    for (int mi = 0; mi < 4; ++mi)
#pragma unroll
      for (int r = 0; r < 4; ++r) {
        int t = mi * 16 + quad * 4 + r;
        dst[t * 32 + (((dg ^ ((t >> 1) & 3)) << 3) | (d & 7))] =
            f2bf(acc[mi][ni][r] + bqv[ni]);
      }
  }
  {
    uint16_t* vdst = qk + 4096;                  // v: [d][64 t], t-granule XOR
#pragma unroll
    for (int ni = 4; ni < 6; ++ni) {
      int d = (ni - 4) * 16 + l15;
#pragma unroll
      for (int mi = 0; mi < 4; ++mi) {
        int t0 = mi * 16 + quad * 4;
        s16x4 pv;
        pv[0] = (short)f2bf(acc[mi][ni][0] + bqv[ni]);
        pv[1] = (short)f2bf(acc[mi][ni][1] + bqv[ni]);
        pv[2] = (short)f2bf(acc[mi][ni][2] + bqv[ni]);
        pv[3] = (short)f2bf(acc[mi][ni][3] + bqv[ni]);
        *(s16x4*)&vdst[d * 64 + (t0 ^ ((d & 7) << 3))] = pv;
      }
    }
  }

  __syncthreads();                               // barrier 2: A dead, qkv ready

  // ---- attention (wave-private): S^T = K*Q^T, column softmax, 2-pass P+PV
  const uint16_t* qb2 = qk;
  const uint16_t* kb2 = qk + 2048;
  const uint16_t* vb2 = qk + 4096;
  const float* bmh = bm + ((size_t)wd * 8 + h) * 4096;

  short8 ak[4], bq[4];
#pragma unroll
  for (int mi = 0; mi < 4; ++mi)
    ak[mi] = *(const short8*)&kb2[(mi * 16 + l15) * 32 + fsw];
#pragma unroll
  for (int ni = 0; ni < 4; ++ni)
    bq[ni] = *(const short8*)&qb2[(ni * 16 + l15) * 32 + fsw];

  f32x4 s[4][4];                                 // S^T: row kk, col q
#pragma unroll
  for (int mi = 0; mi < 4; ++mi)
#pragma unroll
    for (int ni = 0; ni < 4; ++ni)
      s[mi][ni] = __builtin_amdgcn_mfma_f32_16x16x32_bf16(ak[mi], bq[ni], zero, 0, 0, 0);

#pragma unroll
  for (int mi = 0; mi < 4; ++mi)
#pragma unroll
    for (int r = 0; r < 4; ++r) {
      int kk = mi * 16 + quad * 4 + r;
      f32x4 b4 = *(const f32x4*)&bmh[kk * 64 + l15 * 4];
#pragma unroll
      for (int ni = 0; ni < 4; ++ni)
        s[mi][ni][r] = s[mi][ni][r] * SCALE + b4[ni];
    }

  // softmax per column q: 16 in-lane values + 2 shfls
#pragma unroll
  for (int ni = 0; ni < 4; ++ni) {
    float mx = s[0][ni][0];
#pragma unroll
    for (int mi = 0; mi < 4; ++mi)
#pragma unroll
      for (int r = 0; r < 4; ++r) mx = fmaxf(mx, s[mi][ni][r]);
    mx = fmaxf(mx, __shfl_xor(mx, 16, 64));
    mx = fmaxf(mx, __shfl_xor(mx, 32, 64));
    float sum = 0.f;
#pragma unroll
    for (int mi = 0; mi < 4; ++mi)
#pragma unroll
      for (int r = 0; r < 4; ++r) {
        float e = __expf(s[mi][ni][r] - mx);
        s[mi][ni][r] = e;
        sum += e;
      }
    sum += __shfl_xor(sum, 16, 64);
    sum += __shfl_xor(sum, 32, 64);
    float inv = 1.f / sum;
#pragma unroll
    for (int mi = 0; mi < 4; ++mi)
#pragma unroll
      for (int r = 0; r < 4; ++r) s[mi][ni][r] *= inv;
  }

  // 2-pass P (4KB/wave slot in dead A region) + PV. All swizzle bits mod-8,
  // so the 32-row pass offset is transparent.
  uint16_t* Pw = sm + wv * 2048;
  f32x4 o[4][2];
#pragma unroll
  for (int mi = 0; mi < 4; ++mi) { o[mi][0] = zero; o[mi][1] = zero; }
#pragma unroll
  for (int p = 0; p < 2; ++p) {
#pragma unroll
    for (int mi = 0; mi < 4; ++mi)
#pragma unroll
      for (int nn = 0; nn < 2; ++nn) {
        int ni = 2 * p + nn;
        int qp = nn * 16 + l15;                  // local q row 0..31
#pragma unroll
        for (int rp = 0; rp < 2; ++rp) {
          int kk = mi * 16 + quad * 4 + rp * 2;
          uint32_t pk = (uint32_t)f2bf(s[mi][ni][rp * 2]) |
                        ((uint32_t)f2bf(s[mi][ni][rp * 2 + 1]) << 16);
          *(uint32_t*)&Pw[qp * 64 + ((((kk >> 3) ^ (qp & 7)) << 3) | (kk & 7))] = pk;
        }
      }
#pragma unroll
    for (int ki = 0; ki < 2; ++ki) {
      int tc = ki * 32 + quad * 8;
      short8 vf0 = *(const short8*)&vb2[l15 * 64 + (tc ^ ((l15 & 7) << 3))];
      short8 vf1 = *(const short8*)&vb2[(16 + l15) * 64 + (tc ^ ((l15 & 7) << 3))];
#pragma unroll
      for (int mi2 = 0; mi2 < 2; ++mi2) {
        int mi = 2 * p + mi2;
        int qp = mi2 * 16 + l15;
        short8 pa = *(const short8*)&Pw[qp * 64 + (((ki * 4 + quad) ^ (qp & 7)) << 3)];
        o[mi][0] = __builtin_amdgcn_mfma_f32_16x16x32_bf16(pa, vf0, o[mi][0], 0, 0, 0);
        o[mi][1] = __builtin_amdgcn_mfma_f32_16x16x32_bf16(pa, vf1, o[mi][1], 0, 0, 0);
      }
    }
  }

  // ---- AO -> LDS q slot (q dead), [t][32] swizzled, bf16 (same values as
  //      the old HBM AO roundtrip)
  {
    uint16_t* aodst = qk;                        // q slot
#pragma unroll
    for (int ni = 0; ni < 2; ++ni) {
      int d = ni * 16 + l15, dg = d >> 3;
#pragma unroll
      for (int mi = 0; mi < 4; ++mi)
#pragma unroll
        for (int r = 0; r < 4; ++r) {
          int t = mi * 16 + quad * 4 + r;
          aodst[t * 32 + (((dg ^ ((t >> 1) & 3)) << 3) | (d & 7))] = f2bf(o[mi][ni][r]);
        }
    }
  }

  __syncthreads();                               // barrier 3: all AO ready

  // ---- oproj phase: out[t][wv*32..+32) = AO[t][:] @ wo^T + b, scatter.
  //      K chunk ks = head ks's AO slice (head-major = old oproj K-order).
  const uint16_t* bbase2 = wo + (size_t)(wv * 32 + l15) * 256 + quad * 8;
  short8 bfr2[2][2];
#pragma unroll
  for (int ni = 0; ni < 2; ++ni)
    bfr2[0][ni] = *(const short8*)(bbase2 + ni * 4096);

  f32x4 acc2[4][2];
#pragma unroll
  for (int mi = 0; mi < 4; ++mi) { acc2[mi][0] = zero; acc2[mi][1] = zero; }

#pragma unroll
  for (int ks = 0; ks < 8; ++ks) {
    const int cur = ks & 1;
    if (ks < 7) {
#pragma unroll
      for (int ni = 0; ni < 2; ++ni)
        bfr2[cur ^ 1][ni] = *(const short8*)(bbase2 + ni * 4096 + (ks + 1) * 32);
    }
    short8 af2[4];
#pragma unroll
    for (int mi = 0; mi < 4; ++mi)
      af2[mi] = *(const short8*)&sm[16384 + ks * 6144 + (mi * 16 + l15) * 32 + fsw];
#pragma unroll
    for (int mi = 0; mi < 4; ++mi)
#pragma unroll
      for (int ni = 0; ni < 2; ++ni)
        acc2[mi][ni] = __builtin_amdgcn_mfma_f32_16x16x32_bf16(af2[mi], bfr2[cur][ni], acc2[mi][ni], 0, 0, 0);
  }

  float bo4[2];
#pragma unroll
  for (int ni = 0; ni < 2; ++ni) bo4[ni] = bout[wv * 32 + ni * 16 + l15];
  const int hw2 = wd >> 3, ww2 = wd & 7;
#pragma unroll
  for (int mi = 0; mi < 4; ++mi) {
#pragma unroll
    for (int r = 0; r < 4; ++r) {
      int t = mi * 16 + quad * 4 + r;
      int hy = hw2 * 8 + (t >> 3), xx = ww2 * 8 + (t & 7);
      int row = (((hy + 4) & 63) << 6) | ((xx + 4) & 63);  // merge + inverse roll
      float* op = out + ((size_t)bb * 4096 + row) * 256 + wv * 32;
#pragma unroll
      for (int ni = 0; ni < 2; ++ni) op[ni * 16 + l15] = acc2[mi][ni][r] + bo4[ni];
    }
  }
}

extern "C" void kernel_launch(void* const* d_in, const int* in_sizes, int n_in,
                              void* d_out, int out_size, void* d_ws, size_t ws_size,
                              hipStream_t stream) {
  const float* x = (const float*)d_in[0];
  const float* w_qkv = (const float*)d_in[1];
  const float* b_qkv = (const float*)d_in[2];
  const float* w_out = (const float*)d_in[3];
  const float* b_out = (const float*)d_in[4];
  const float* pos_enc = (const float*)d_in[5];
  float* out = (float*)d_out;

  uint8_t* ws = (uint8_t*)d_ws;
  uint16_t* wqb = (uint16_t*)(ws);                 //   393,216 B
  uint16_t* wob = (uint16_t*)(ws + 393216);        //   131,072 B (contig w/ wqb)
  float*    bmt = (float*)   (ws + 524288);        // 8,388,608 B

  cvtw_kernel<<<128, 256, 0, stream>>>(w_qkv, w_out, wqb);
  bias_kernel<<<512, 256, 0, stream>>>(pos_enc, bmt);
  swattn_kernel<<<2048, 512, 0, stream>>>(x, wqb, wob, b_qkv, b_out, bmt, out);
}

// Round 8
// 371.124 us; speedup vs baseline: 1.0986x; 1.0986x over previous
//
#include <hip/hip_runtime.h>
#include <stdint.h>

// ---------------------------------------------------------------------------
// ShiftedWindowAttention: B=32, H=W=64, C=256, heads=8, hd=32, ws=8, shift=4.
// Pipeline (v7 = v5.1 skeleton, occupancy + epilogue-addressing rework):
//   cvtw  (weights f32->bf16, merged wqkv+wout)
//   bias  (pos_enc -> transposed/interleaved bias+mask table, f32)
//   wattn (FUSED cvtx+qkv+attn per (window, head-half), 4 waves, 48 KB LDS ->
//          3 blocks/CU: A staged in two 16KB K-halves; k/v only persistent
//          (8KB/wave); q transposed through dead A region, slot reused as P
//          (2-pass P/PV, v6-verified); affine (t>>2) epilogue swizzle)
//   oproj (GEMM 131072x256x256 + merge/inv-roll scatter, v3 dbuf form)
// ---------------------------------------------------------------------------

typedef short short8 __attribute__((ext_vector_type(8)));
typedef short s16x4 __attribute__((ext_vector_type(4)));
typedef float f32x4 __attribute__((ext_vector_type(4)));

typedef __attribute__((address_space(1))) uint32_t g_u32;
typedef __attribute__((address_space(3))) uint32_t l_u32;

#define SCALE 0.17677669529663687f

__device__ __forceinline__ uint16_t f2bf(float f) {
  union { float f; uint32_t u; } c; c.f = f;
  uint32_t r = c.u + 0x7FFFu + ((c.u >> 16) & 1u);   // RNE
  return (uint16_t)(r >> 16);
}

__device__ __forceinline__ void g2lds16(const void* g, void* l) {
  __builtin_amdgcn_global_load_lds((const g_u32*)g, (l_u32*)l, 16, 0, 0);
}

// ---- weights f32 -> bf16 (wqkv and wout merged; outputs contiguous in ws)
__global__ __launch_bounds__(256) void cvtw_kernel(const float* __restrict__ wq,
                                                   const float* __restrict__ wo,
                                                   uint16_t* __restrict__ out) {
  int i = (blockIdx.x * 256 + threadIdx.x) * 8;       // grid 128 -> 262144 elems
  const float* src = (i < 196608) ? (wq + i) : (wo + (i - 196608));
  f32x4 a = *(const f32x4*)src;
  f32x4 b = *(const f32x4*)(src + 4);
  short8 v;
  v[0] = (short)f2bf(a[0]); v[1] = (short)f2bf(a[1]);
  v[2] = (short)f2bf(a[2]); v[3] = (short)f2bf(a[3]);
  v[4] = (short)f2bf(b[0]); v[5] = (short)f2bf(b[1]);
  v[6] = (short)f2bf(b[2]); v[7] = (short)f2bf(b[3]);
  *(short8*)(out + i) = v;
}

// ---- bias+mask table, transposed+interleaved: bm[wd][head][kk][a(16)][ni(4)]
__global__ __launch_bounds__(256) void bias_kernel(const float* __restrict__ pe,
                                                   float* __restrict__ bm) {
  int bx = blockIdx.x;              // wd*8 + head
  int wd = bx >> 3, head = bx & 7;
  int hw = wd >> 3, ww = wd & 7;
  int tid = threadIdx.x;
  int kk = tid >> 2, a0 = (tid & 3) * 4;
  int jy = kk >> 3, jx = kk & 7;
  int hj = hw * 8 + jy, xj = ww * 8 + jx;
  int rj = (hj >= 60 ? 2 : (hj >= 56 ? 1 : 0)) * 3 + (xj >= 60 ? 2 : (xj >= 56 ? 1 : 0));
  float* dst = bm + (size_t)bx * 4096 + kk * 64 + a0 * 4;
  for (int aa = 0; aa < 4; ++aa) {
    int a = a0 + aa;
    f32x4 v;
#pragma unroll
    for (int ni = 0; ni < 4; ++ni) {
      int i = ni * 16 + a;
      int iy = i >> 3, ix = i & 7;
      int hi = hw * 8 + iy, xi = ww * 8 + ix;
      int ri = (hi >= 60 ? 2 : (hi >= 56 ? 1 : 0)) * 3 + (xi >= 60 ? 2 : (xi >= 56 ? 1 : 0));
      v[ni] = (ri != rj) ? -1e30f : pe[head * 225 + (iy - jy + 7) * 15 + (ix - jx + 7)];
    }
    *(f32x4*)(dst + aa * 4) = v;
  }
}

// ---- FUSED cvtx + qkv + attention. One block per (window, head-half).
//      4 waves (wave = head). 48 KB LDS -> 3 blocks/CU.
__global__ __launch_bounds__(256, 3) void wattn_kernel(
    const float* __restrict__ x, const uint16_t* __restrict__ wq,
    const float* __restrict__ bqkv, const float* __restrict__ bm,
    uint16_t* __restrict__ ao) {
  __shared__ uint16_t sm[24576];                 // 48 KB
  uint16_t* As = sm;                             // [4 ksl][64 t][32 k] swz (16KB); later q/P scratch
  const int tid = threadIdx.x, lane = tid & 63, wv = tid >> 6;
  const int quad = lane >> 4, l15 = lane & 15;
  const int b = blockIdx.x;
  const int w = ((b >> 4) << 3) + (b & 7);       // window (hh-pairs 8 apart: same XCD)
  const int hh = (b >> 3) & 1;                   // head half
  const int h = hh * 4 + wv;                     // this wave's head
  const int wd = w & 63, bb = w >> 6;
  f32x4 zero = {0.f, 0.f, 0.f, 0.f};

  // per-thread x source row (roll(-4,-4) + window gather), staged in K-halves
  const int srow = tid >> 2, scg = tid & 3;      // 64 rows, 4 threads/row
  const float* sp;
  {
    int hy = (wd >> 3) * 8 + (srow >> 3);
    int xx = (wd & 7) * 8 + (srow & 7);
    sp = x + (size_t)(bb * 4096 + (((hy + 4) & 63) << 6) + ((xx + 4) & 63)) * 256;
  }
  const int spsw = (srow >> 1) & 3;

  // B rows for this wave: sec*65536 + (h*32 + (ni&1)*16 + l15)*256, 16B @quad*8
  const uint16_t* bb0 = wq + (size_t)(h * 32 + l15) * 256 + quad * 8;
  short8 bfr[2][6];
#pragma unroll
  for (int ni = 0; ni < 6; ++ni)
    bfr[0][ni] = *(const short8*)(bb0 + (ni >> 1) * 65536 + (ni & 1) * 4096);

  f32x4 acc[4][6];
#pragma unroll
  for (int mi = 0; mi < 4; ++mi)
#pragma unroll
    for (int ni = 0; ni < 6; ++ni) acc[mi][ni] = zero;

  const int fsw = (quad ^ ((l15 >> 1) & 3)) << 3;   // A frag granule (matches spsw)

  for (int hf = 0; hf < 2; ++hf) {
    if (hf) __syncthreads();                     // all waves done reading half 0
    // ---- stage half hf: 64 rows x 128 cols f32 -> bf16 -> swizzled LDS
#pragma unroll
    for (int j = 0; j < 4; ++j) {
      int c0 = scg * 8 + j * 32;                 // col within half; ksl = j, g = scg
      const float* p = sp + hf * 128 + c0;
      f32x4 a = *(const f32x4*)p;
      f32x4 d = *(const f32x4*)(p + 4);
      short8 v;
      v[0] = (short)f2bf(a[0]); v[1] = (short)f2bf(a[1]);
      v[2] = (short)f2bf(a[2]); v[3] = (short)f2bf(a[3]);
      v[4] = (short)f2bf(d[0]); v[5] = (short)f2bf(d[1]);
      v[6] = (short)f2bf(d[2]); v[7] = (short)f2bf(d[3]);
      *(short8*)&As[(j * 64 + srow) * 32 + ((scg ^ spsw) << 3)] = v;
    }
    __syncthreads();                             // half resident
#pragma unroll
    for (int ksl = 0; ksl < 4; ++ksl) {
      const int ks = hf * 4 + ksl;
      const int cur = ks & 1;
      if (ks < 7) {                              // continuous B register prefetch
#pragma unroll
        for (int ni = 0; ni < 6; ++ni)
          bfr[cur ^ 1][ni] = *(const short8*)(bb0 + (ni >> 1) * 65536 + (ni & 1) * 4096 + (ks + 1) * 32);
      }
      short8 af[4];
#pragma unroll
      for (int mi = 0; mi < 4; ++mi)
        af[mi] = *(const short8*)&As[(ksl * 64 + mi * 16 + l15) * 32 + fsw];
#pragma unroll
      for (int mi = 0; mi < 4; ++mi)
#pragma unroll
        for (int ni = 0; ni < 6; ++ni)
          acc[mi][ni] = __builtin_amdgcn_mfma_f32_16x16x32_bf16(af[mi], bfr[cur][ni], acc[mi][ni], 0, 0, 0);
    }
  }

  // ---- k/v epilogue into wave-private slice (no barrier needed)
  uint16_t* kvs = sm + 8192 + wv * 4096;         // k [0,2048) | v [2048,4096)
  float bqv[6];
#pragma unroll
  for (int ni = 0; ni < 6; ++ni)
    bqv[ni] = bqkv[(ni >> 1) * 256 + h * 32 + (ni & 1) * 16 + l15];

  // k: [t][32], granule = dg ^ quad ((t>>2) swizzle -> affine in mi,r)
#pragma unroll
  for (int ni = 2; ni < 4; ++ni) {
    int d = (ni & 1) * 16 + l15;
    uint16_t* kd = kvs + quad * 4 * 32 + ((((d >> 3) ^ quad) << 3) | (d & 7));
#pragma unroll
    for (int mi = 0; mi < 4; ++mi)
#pragma unroll
      for (int r = 0; r < 4; ++r)
        kd[mi * 512 + r * 32] = f2bf(acc[mi][ni][r] + bqv[ni]);
  }
  // v: [d][64 t], t-granule XOR, b64-packed writes
  {
    uint16_t* vdst = kvs + 2048;
#pragma unroll
    for (int ni = 4; ni < 6; ++ni) {
      int d = (ni - 4) * 16 + l15;
#pragma unroll
      for (int mi = 0; mi < 4; ++mi) {
        int t0 = mi * 16 + quad * 4;
        s16x4 pv;
        pv[0] = (short)f2bf(acc[mi][ni][0] + bqv[ni]);
        pv[1] = (short)f2bf(acc[mi][ni][1] + bqv[ni]);
        pv[2] = (short)f2bf(acc[mi][ni][2] + bqv[ni]);
        pv[3] = (short)f2bf(acc[mi][ni][3] + bqv[ni]);
        *(s16x4*)&vdst[d * 64 + (t0 ^ ((d & 7) << 3))] = pv;
      }
    }
  }

  __syncthreads();                               // A region dead everywhere

  // ---- q transpose through scratch (dead A region, wave-private 4KB)
  uint16_t* sq = sm + wv * 2048;
#pragma unroll
  for (int ni = 0; ni < 2; ++ni) {
    int d = ni * 16 + l15;
    uint16_t* qd = sq + quad * 4 * 32 + ((((d >> 3) ^ quad) << 3) | (d & 7));
#pragma unroll
    for (int mi = 0; mi < 4; ++mi)
#pragma unroll
      for (int r = 0; r < 4; ++r)
        qd[mi * 512 + r * 32] = f2bf(acc[mi][ni][r] + bqv[ni]);
  }

  const int fsw2 = (quad ^ ((l15 >> 2) & 3)) << 3;  // (t>>2)-swizzle frag read
  short8 bq[4], ak[4];
#pragma unroll
  for (int ni = 0; ni < 4; ++ni)
    bq[ni] = *(const short8*)&sq[(ni * 16 + l15) * 32 + fsw2];
#pragma unroll
  for (int mi = 0; mi < 4; ++mi)
    ak[mi] = *(const short8*)&kvs[(mi * 16 + l15) * 32 + fsw2];

  // ---- S^T = K*Q^T, scale+bias, column softmax
  const float* bmh = bm + ((size_t)wd * 8 + h) * 4096;
  f32x4 s[4][4];
#pragma unroll
  for (int mi = 0; mi < 4; ++mi)
#pragma unroll
    for (int ni = 0; ni < 4; ++ni)
      s[mi][ni] = __builtin_amdgcn_mfma_f32_16x16x32_bf16(ak[mi], bq[ni], zero, 0, 0, 0);

#pragma unroll
  for (int mi = 0; mi < 4; ++mi)
#pragma unroll
    for (int r = 0; r < 4; ++r) {
      int kk = mi * 16 + quad * 4 + r;
      f32x4 b4 = *(const f32x4*)&bmh[kk * 64 + l15 * 4];
#pragma unroll
      for (int ni = 0; ni < 4; ++ni)
        s[mi][ni][r] = s[mi][ni][r] * SCALE + b4[ni];
    }

#pragma unroll
  for (int ni = 0; ni < 4; ++ni) {
    float mx = s[0][ni][0];
#pragma unroll
    for (int mi = 0; mi < 4; ++mi)
#pragma unroll
      for (int r = 0; r < 4; ++r) mx = fmaxf(mx, s[mi][ni][r]);
    mx = fmaxf(mx, __shfl_xor(mx, 16, 64));
    mx = fmaxf(mx, __shfl_xor(mx, 32, 64));
    float sum = 0.f;
#pragma unroll
    for (int mi = 0; mi < 4; ++mi)
#pragma unroll
      for (int r = 0; r < 4; ++r) {
        float e = __expf(s[mi][ni][r] - mx);
        s[mi][ni][r] = e;
        sum += e;
      }
    sum += __shfl_xor(sum, 16, 64);
    sum += __shfl_xor(sum, 32, 64);
    float inv = 1.f / sum;
#pragma unroll
    for (int mi = 0; mi < 4; ++mi)
#pragma unroll
      for (int r = 0; r < 4; ++r) s[mi][ni][r] *= inv;
  }

  // ---- 2-pass P (scratch slot, q dead after bq read) + PV  [v6-verified]
  uint16_t* Pw = sq;
  const uint16_t* vb2 = kvs + 2048;
  f32x4 o[4][2];
#pragma unroll
  for (int mi = 0; mi < 4; ++mi) { o[mi][0] = zero; o[mi][1] = zero; }
#pragma unroll
  for (int p = 0; p < 2; ++p) {
#pragma unroll
    for (int mi = 0; mi < 4; ++mi)
#pragma unroll
      for (int nn = 0; nn < 2; ++nn) {
        int ni = 2 * p + nn;
        int qp = nn * 16 + l15;                  // local q row 0..31
#pragma unroll
        for (int rp = 0; rp < 2; ++rp) {
          int kk = mi * 16 + quad * 4 + rp * 2;
          uint32_t pk = (uint32_t)f2bf(s[mi][ni][rp * 2]) |
                        ((uint32_t)f2bf(s[mi][ni][rp * 2 + 1]) << 16);
          *(uint32_t*)&Pw[qp * 64 + ((((kk >> 3) ^ (qp & 7)) << 3) | (kk & 7))] = pk;
        }
      }
#pragma unroll
    for (int ki = 0; ki < 2; ++ki) {
      int tc = ki * 32 + quad * 8;
      short8 vf0 = *(const short8*)&vb2[l15 * 64 + (tc ^ ((l15 & 7) << 3))];
      short8 vf1 = *(const short8*)&vb2[(16 + l15) * 64 + (tc ^ ((l15 & 7) << 3))];
#pragma unroll
      for (int mi2 = 0; mi2 < 2; ++mi2) {
        int mi = 2 * p + mi2;
        int qp = mi2 * 16 + l15;
        short8 pa = *(const short8*)&Pw[qp * 64 + (((ki * 4 + quad) ^ (qp & 7)) << 3)];
        o[mi][0] = __builtin_amdgcn_mfma_f32_16x16x32_bf16(pa, vf0, o[mi][0], 0, 0, 0);
        o[mi][1] = __builtin_amdgcn_mfma_f32_16x16x32_bf16(pa, vf1, o[mi][1], 0, 0, 0);
      }
    }
  }

  // ---- AO write (bf16, [token][256])
#pragma unroll
  for (int mi = 0; mi < 4; ++mi)
#pragma unroll
    for (int ni = 0; ni < 2; ++ni)
#pragma unroll
      for (int r = 0; r < 4; ++r) {
        int t = mi * 16 + quad * 4 + r;
        ao[(size_t)(w * 64 + t) * 256 + h * 32 + ni * 16 + l15] = f2bf(o[mi][ni][r]);
      }
}

// ---- out-proj GEMM: out[131072,256] = AO @ wo^T + b, + merge/inv-roll scatter
//      Double-buffered, top-barrier/issue-after scheme (v3, measured-good).
__global__ __launch_bounds__(256) void oproj_kernel(
    const uint16_t* __restrict__ aob, const uint16_t* __restrict__ wo,
    const float* __restrict__ bout, float* __restrict__ out) {
  __shared__ uint16_t sm[16384];                 // 32 KB: A dbuf 16 + B dbuf 16
  uint16_t* As = sm;                             // [2][128][32]
  uint16_t* Bs = sm + 8192;                      // [2][128][32]
  const int tid = threadIdx.x, lane = tid & 63, wv = tid >> 6;
  const int quad = lane >> 4, l15 = lane & 15;
  const int n0 = blockIdx.x * 128;
  const int m0 = blockIdx.y * 128;

  const int c0 = wv * 2, c1 = c0 + 1;
  const int perm = ((lane & 3) ^ ((lane >> 3) & 3)) * 8;
  const int fsw = (quad ^ ((l15 >> 1) & 3)) * 8;
  const uint16_t* ap0 = aob + (size_t)(m0 + c0 * 16 + (lane >> 2)) * 256 + perm;
  const uint16_t* ap1 = aob + (size_t)(m0 + c1 * 16 + (lane >> 2)) * 256 + perm;
  const uint16_t* bp0 = wo + (size_t)(n0 + c0 * 16 + (lane >> 2)) * 256 + perm;
  const uint16_t* bp1 = wo + (size_t)(n0 + c1 * 16 + (lane >> 2)) * 256 + perm;

  const int wm = (wv & 1) * 64, wn = (wv >> 1) * 64;
  f32x4 zero = {0.f, 0.f, 0.f, 0.f};
  f32x4 acc[4][4];
#pragma unroll
  for (int mi = 0; mi < 4; ++mi)
#pragma unroll
    for (int ni = 0; ni < 4; ++ni) acc[mi][ni] = zero;

  // prologue: ks=0 into buf0
  g2lds16(ap0, &As[c0 * 512]);
  g2lds16(ap1, &As[c1 * 512]);
  g2lds16(bp0, &Bs[c0 * 512]);
  g2lds16(bp1, &Bs[c1 * 512]);

#pragma unroll
  for (int ks = 0; ks < 8; ++ks) {
    __syncthreads();                             // drains loads issued a phase ago
    if (ks < 7) {
      int nb = ((ks + 1) & 1) * 4096, k0 = (ks + 1) * 32;
      g2lds16(ap0 + k0, &As[nb + c0 * 512]);
      g2lds16(ap1 + k0, &As[nb + c1 * 512]);
      g2lds16(bp0 + k0, &Bs[nb + c0 * 512]);
      g2lds16(bp1 + k0, &Bs[nb + c1 * 512]);
    }
    int buf = (ks & 1) * 4096;
    short8 af[4], bf[4];
#pragma unroll
    for (int mi = 0; mi < 4; ++mi)
      af[mi] = *(const short8*)&As[buf + (wm + mi * 16 + l15) * 32 + fsw];
#pragma unroll
    for (int ni = 0; ni < 4; ++ni)
      bf[ni] = *(const short8*)&Bs[buf + (wn + ni * 16 + l15) * 32 + fsw];
#pragma unroll
    for (int mi = 0; mi < 4; ++mi)
#pragma unroll
      for (int ni = 0; ni < 4; ++ni)
        acc[mi][ni] = __builtin_amdgcn_mfma_f32_16x16x32_bf16(af[mi], bf[ni], acc[mi][ni], 0, 0, 0);
  }

  float bo4[4];
#pragma unroll
  for (int ni = 0; ni < 4; ++ni) bo4[ni] = bout[n0 + wn + ni * 16 + l15];
#pragma unroll
  for (int mi = 0; mi < 4; ++mi) {
    int mb = m0 + wm + mi * 16 + quad * 4;
    int w = mb >> 6, t0 = mb & 63;
    int b = w >> 6, wd = w & 63;
    int hw2 = wd >> 3, ww2 = wd & 7;
#pragma unroll
    for (int r = 0; r < 4; ++r) {
      int t = t0 + r;
      int h = hw2 * 8 + (t >> 3), xx = ww2 * 8 + (t & 7);
      int row = (((h + 4) & 63) << 6) | ((xx + 4) & 63);   // merge + inverse roll
      float* op = out + ((size_t)b * 4096 + row) * 256 + n0 + wn;
#pragma unroll
      for (int ni = 0; ni < 4; ++ni) op[ni * 16 + l15] = acc[mi][ni][r] + bo4[ni];
    }
  }
}

extern "C" void kernel_launch(void* const* d_in, const int* in_sizes, int n_in,
                              void* d_out, int out_size, void* d_ws, size_t ws_size,
                              hipStream_t stream) {
  const float* x = (const float*)d_in[0];
  const float* w_qkv = (const float*)d_in[1];
  const float* b_qkv = (const float*)d_in[2];
  const float* w_out = (const float*)d_in[3];
  const float* b_out = (const float*)d_in[4];
  const float* pos_enc = (const float*)d_in[5];
  float* out = (float*)d_out;

  uint8_t* ws = (uint8_t*)d_ws;
  uint16_t* aob = (uint16_t*)(ws);                 // 67,108,864 B (AO)
  uint16_t* wqb = (uint16_t*)(ws + 67108864);      //    393,216 B
  uint16_t* wob = (uint16_t*)(ws + 67502080);      //    131,072 B (contig w/ wqb)
  float*    bmt = (float*)   (ws + 67633152);      //  8,388,608 B

  cvtw_kernel<<<128, 256, 0, stream>>>(w_qkv, w_out, wqb);
  bias_kernel<<<512, 256, 0, stream>>>(pos_enc, bmt);
  wattn_kernel<<<4096, 256, 0, stream>>>(x, wqb, b_qkv, bmt, aob);
  oproj_kernel<<<dim3(2, 1024), 256, 0, stream>>>(aob, wob, b_out, out);
}